// Round 12
// baseline (596.214 us; speedup 1.0000x reference)
//
#include <hip/hip_runtime.h>
#include <hip/hip_bf16.h>

#define FDIM 15
#define HDIM 128
#define LNUM 12
#define NBINS 16
#define MDIM 47
#define FM 705
#define BATCH 65536
#define TAILF 3.0f
#define MIN_Wc 0.001f
#define MIN_Hc 0.001f
#define MIN_Dc 0.001f

typedef __bf16 bf16_t;
typedef __attribute__((ext_vector_type(8))) __bf16 bf16x8;
typedef __attribute__((ext_vector_type(4))) __bf16 bf16x4;
typedef __attribute__((ext_vector_type(4))) float f32x4;

// densely packed fragment stream: 316 frags/layer, 12 layers = 3792 frags
#define FRAGS_L 316
#define FRAG_ELEMS 512            // 64 lanes * 8 bf16 = 1 KB
#define CHUNK_FRAGS 8
#define CHUNK_ELEMS (CHUNK_FRAGS * FRAG_ELEMS)   // 8 KB
#define NCHUNKS_TOT (LNUM * FRAGS_L / CHUNK_FRAGS)   // 474 exactly
#define WFRAG_TOTAL (LNUM * FRAGS_L * FRAG_ELEMS)

// bias blob per layer: bI(128) | bR(512) | bOpad(15*48=720) = 1360 floats
#define BB_FLOATS 1360
#define BB_TOTAL (LNUM * BB_FLOATS)

#define SPW 32                    // samples per wave (2 N-tiles of 16)

// LDS pool layout (bytes)
#define WBUF_OFF   0
#define WBUF_BYTES (2 * CHUNK_ELEMS * 2)           // 16384 (ring of 16 frags)
#define XSS_OFF    WBUF_BYTES
#define XSS_BYTES  (4 * SPW * 17 * 4)              // 8704
#define UNION_OFF  (XSS_OFF + XSS_BYTES)           // per-wave max(Bst 8704, raw 13312)
#define UNION_WV   13312
#define POOL_BYTES (UNION_OFF + 4 * UNION_WV)      // 78336

__device__ __forceinline__ float sp_softplus(float u) {
    return (u > 20.f) ? u : __logf(1.f + __expf(u));
}

// ---------------- preproc: densely packed wfrag + padded bias blob ----------------
__global__ void preproc_kernel(const float* __restrict__ Wi,
                               const float* __restrict__ Wr,
                               const float* __restrict__ Wo,
                               const float* __restrict__ bIg,
                               const float* __restrict__ bRg,
                               const float* __restrict__ bOg,
                               bf16_t* __restrict__ wfrag,
                               float* __restrict__ bblob) {
    int idx = blockIdx.x * blockDim.x + threadIdx.x;
    if (idx >= WFRAG_TOTAL) {
        int t = idx - WFRAG_TOTAL;
        if (t >= BB_TOTAL) return;
        int l = t / BB_FLOATS, r = t % BB_FLOATS;
        float v;
        if (r < 128) v = bIg[l * HDIM + r];
        else if (r < 640) v = bRg[l * 4 * HDIM + (r - 128)];
        else {
            int q = r - 640, f = q / 48, j = q % 48;
            v = (j < 47) ? bOg[(size_t)l * FM + f * MDIM + j] : 0.f;
        }
        bblob[t] = v;
        return;
    }
    int j = idx & 7;
    int lane = (idx >> 3) & 63;
    int fg = idx >> 9;
    int g = fg % FRAGS_L;
    int l = fg / FRAGS_L;
    int quad = lane >> 4, n16 = lane & 15;
    int kk = quad * 8 + j;
    float val = 0.f;
    if (g < 8) {
        int n = g * 16 + n16;
        if (kk < FDIM && (n % 14) >= kk)
            val = Wi[(l * HDIM + n) * FDIM + kk];
    } else if (g < 136) {
        int gg = g - 8;
        int mat = gg >> 5, rem = gg & 31, nt = rem >> 2, s = rem & 3;
        int k = s * 32 + kk;
        int jc = nt * 16 + n16;
        if ((jc % 14) >= (k % 14))
            val = Wr[((size_t)(l * 4 + mat) * HDIM + jc) * HDIM + k];
    } else {
        int gg = g - 136;
        int tt = gg >> 2, s = gg & 3;
        int k = s * 32 + kk;
        int f = tt / 3, ty = tt % 3;
        int o = (ty < 2) ? (f * MDIM + ty * 16 + n16)
                         : ((n16 < 15) ? (f * MDIM + 32 + n16) : -1);
        if (o >= 0 && (f + 1) > (k % 14 + 1))
            val = Wo[((size_t)l * FM + o) * HDIM + k];
    }
    wfrag[idx] = (bf16_t)val;
}

// ---------------- fused 12-layer flow kernel: continuous weight ring ----------------
__global__ __launch_bounds__(256, 2) void flow_kernel(
    const float* __restrict__ xin,
    float* __restrict__ out,
    const bf16_t* __restrict__ wfrag,
    const float* __restrict__ bb) {

    __shared__ __align__(16) unsigned char pool[POOL_BYTES];

    const int tid = threadIdx.x;
    const int wv = tid >> 6, ln = tid & 63;
    const int quad = ln >> 4, n16 = ln & 15;
    const int fi = ln & 1, srow = ln >> 1;
    const int sbase = (blockIdx.x * 4 + wv) * SPW;

    char*   wbufc = (char*)(pool + WBUF_OFF);
    bf16_t* wbuf  = (bf16_t*)wbufc;
    float*  xs    = (float*)(pool + XSS_OFF) + wv * SPW * 17;      // [32][17]
    bf16_t* Bst   = (bf16_t*)(pool + UNION_OFF + wv * UNION_WV);   // [32][136]
    float*  raw   = (float*)(pool + UNION_OFF + wv * UNION_WV);    // [2][32][52]

    auto dma_chunk = [&](int sl, const bf16_t* g) {
#pragma unroll
        for (int i = 0; i < 2; i++) {
            int off = (i * 4 + wv) * FRAG_ELEMS;   // wave-uniform LDS dest
            __builtin_amdgcn_global_load_lds(
                (const __attribute__((address_space(1))) uint32_t*)(g + off + ln * 8),
                (__attribute__((address_space(3))) uint32_t*)(wbuf + sl * CHUNK_ELEMS + off), 16, 0, 0);
        }
    };

    dma_chunk(0, wfrag);
    dma_chunk(1, wfrag + CHUNK_ELEMS);
    const bf16_t* gnext = wfrag + 2 * CHUNK_ELEMS;
    const bf16_t* gend  = wfrag + (size_t)NCHUNKS_TOT * CHUNK_ELEMS;
    int pslot = 0;                 // slot for next prefetch
    int fcnt = 0;                  // frags consumed in current chunk
    unsigned rpos = ln * 16;       // this lane's next frag byte offset in ring

    // load x (32 samples x 15)
    for (int t = ln; t < SPW * FDIM; t += 64) {
        int s = t / FDIM, i = t % FDIM;
        xs[s * 17 + i] = xin[(size_t)(sbase + s) * FDIM + i];
    }

    __syncthreads();   // xs visible + chunks 0,1 drained

    auto nextfrag = [&]() -> bf16x8 {
        if (fcnt == CHUNK_FRAGS) {
            __syncthreads();
            if (gnext < gend) { dma_chunk(pslot, gnext); gnext += CHUNK_ELEMS; pslot ^= 1; }
            fcnt = 0;
        }
        bf16x8 r = *(const bf16x8*)(wbufc + rpos);
        rpos = (rpos + 1024) & (WBUF_BYTES - 1);
        fcnt++;
        return r;
    };

    f32x4 h[2][8];
    bf16x8 bf[2][4];

    auto stageB = [&](const f32x4 (*src)[8], bool relu) {
#pragma unroll
        for (int T = 0; T < 2; T++)
#pragma unroll
            for (int mt = 0; mt < 8; mt++) {
                bf16x4 pk;
#pragma unroll
                for (int r = 0; r < 4; r++) {
                    float v = src[T][mt][r];
                    if (relu) v = fmaxf(v, 0.f);
                    pk[r] = (bf16_t)v;
                }
                *(bf16x4*)&Bst[(T * 16 + n16) * 136 + mt * 16 + quad * 4] = pk;
            }
#pragma unroll
        for (int T = 0; T < 2; T++)
#pragma unroll
            for (int s = 0; s < 4; s++)
                bf[T][s] = *(const bf16x8*)&Bst[(T * 16 + n16) * 136 + s * 32 + quad * 8];
    };

    auto gemm128 = [&](f32x4 (*dst)[8], const float* bias_m, bool addto) {
        f32x4 bbv[8];
#pragma unroll
        for (int mt = 0; mt < 8; mt++)
            bbv[mt] = *(const f32x4*)&bias_m[mt * 16 + quad * 4];
#pragma unroll
        for (int mt = 0; mt < 8; mt++) {
            f32x4 acc0 = addto ? (dst[0][mt] + bbv[mt]) : bbv[mt];
            f32x4 acc1 = addto ? (dst[1][mt] + bbv[mt]) : bbv[mt];
#pragma unroll
            for (int s = 0; s < 4; s++) {
                bf16x8 wf = nextfrag();
                acc0 = __builtin_amdgcn_mfma_f32_16x16x32_bf16(wf, bf[0][s], acc0, 0, 0, 0);
                acc1 = __builtin_amdgcn_mfma_f32_16x16x32_bf16(wf, bf[1][s], acc1, 0, 0, 0);
            }
            dst[0][mt] = acc0;
            dst[1][mt] = acc1;
        }
    };

    float lad_acc = 0.f;

    for (int l = 0; l < LNUM; l++) {
        const float* bias = bb + l * BB_FLOATS;

        // spline x-inputs (reversed frame): round p handles features 2p+fi
        float xc_pre[8];
#pragma unroll
        for (int p = 0; p < 8; p++) {
            int f = 2 * p + fi;
            xc_pre[p] = xs[srow * 17 + ((f < FDIM) ? (14 - f) : 0)];
        }
        // init-GEMM act B fragments from reversed xs, K padded 15->32
        bf16x8 a0[2];
#pragma unroll
        for (int T = 0; T < 2; T++)
#pragma unroll
            for (int j = 0; j < 8; j++) {
                int k = quad * 8 + j;
                a0[T][j] = (bf16_t)((k < FDIM) ? xs[(T * 16 + n16) * 17 + 14 - k] : 0.f);
            }

        // ---- init GEMM (frags 0..7)
        {
            f32x4 bbv[8];
#pragma unroll
            for (int mt = 0; mt < 8; mt++)
                bbv[mt] = *(const f32x4*)&bias[mt * 16 + quad * 4];
#pragma unroll
            for (int mt = 0; mt < 8; mt++) {
                bf16x8 wf = nextfrag();
                h[0][mt] = __builtin_amdgcn_mfma_f32_16x16x32_bf16(wf, a0[0], bbv[mt], 0, 0, 0);
                h[1][mt] = __builtin_amdgcn_mfma_f32_16x16x32_bf16(wf, a0[1], bbv[mt], 0, 0, 0);
            }
        }

        // ---- residual blocks (frags 8..135)
        {
            f32x4 t[2][8];
            stageB(h, true);
            gemm128(t, bias + 128 + 0 * HDIM, false);
            stageB(t, true);
            gemm128(h, bias + 128 + 1 * HDIM, true);
            stageB(h, true);
            gemm128(t, bias + 128 + 2 * HDIM, false);
            stageB(t, true);
            gemm128(h, bias + 128 + 3 * HDIM, true);
        }

        // ---- out GEMM (frags 136..315) in 2-feature rounds + spline
        stageB(h, false);          // bf final; Bst region becomes raw
        const float* bO48 = bias + 640;

#pragma unroll
        for (int p = 0; p < 8; p++) {
            const int nf = (p < 7) ? 2 : 1;
            for (int ff = 0; ff < nf; ff++) {
                int f = 2 * p + ff;
                f32x4 bb3[3];
#pragma unroll
                for (int ty = 0; ty < 3; ty++)
                    bb3[ty] = *(const f32x4*)&bO48[f * 48 + ty * 16 + quad * 4];
#pragma unroll
                for (int ty = 0; ty < 3; ty++) {
                    f32x4 acc0 = bb3[ty];
                    f32x4 acc1 = bb3[ty];
#pragma unroll
                    for (int s = 0; s < 4; s++) {
                        bf16x8 wf = nextfrag();
                        acc0 = __builtin_amdgcn_mfma_f32_16x16x32_bf16(wf, bf[0][s], acc0, 0, 0, 0);
                        acc1 = __builtin_amdgcn_mfma_f32_16x16x32_bf16(wf, bf[1][s], acc1, 0, 0, 0);
                    }
                    // raw rows = ff*32 + sample (bank-uniform)
                    *(f32x4*)&raw[(ff * 32 + n16) * 52 + ty * 16 + quad * 4] = acc0;
                    *(f32x4*)&raw[(ff * 32 + 16 + n16) * 52 + ty * 16 + quad * 4] = acc1;
                }
            }

            // spline: lanes fi<nf handle (sample srow, feature 2p+fi)
            if (fi < nf) {
                int f = 2 * p + fi;
                const float* rp = &raw[(fi * 32 + srow) * 52];
                float xr = xc_pre[p];
                bool inside = (xr >= -TAILF) && (xr <= TAILF);
                float xcv = fminf(fmaxf(xr, -TAILF), TAILF);

                float uw[NBINS], uh[NBINS];
                {
                    f32x4 v0 = *(const f32x4*)(rp + 0);
                    f32x4 v1 = *(const f32x4*)(rp + 4);
                    f32x4 v2 = *(const f32x4*)(rp + 8);
                    f32x4 v3 = *(const f32x4*)(rp + 12);
                    f32x4 w0 = *(const f32x4*)(rp + 16);
                    f32x4 w1 = *(const f32x4*)(rp + 20);
                    f32x4 w2 = *(const f32x4*)(rp + 24);
                    f32x4 w3 = *(const f32x4*)(rp + 28);
#pragma unroll
                    for (int i = 0; i < 4; i++) {
                        uw[i] = v0[i]; uw[4 + i] = v1[i]; uw[8 + i] = v2[i]; uw[12 + i] = v3[i];
                        uh[i] = w0[i]; uh[4 + i] = w1[i]; uh[8 + i] = w2[i]; uh[12 + i] = w3[i];
                    }
                }
                float mw = -1e30f, mh = -1e30f;
#pragma unroll
                for (int i = 0; i < NBINS; i++) {
                    mw = fmaxf(mw, uw[i]); mh = fmaxf(mh, uh[i]);
                }
                float swv = 0.f, shv = 0.f;
#pragma unroll
                for (int i = 0; i < NBINS; i++) {
                    uw[i] = __expf(uw[i] - mw); swv += uw[i];
                    uh[i] = __expf(uh[i] - mh); shv += uh[i];
                }
                float isw = (1.f - NBINS * MIN_Wc) / swv;
                float ish = (1.f - NBINS * MIN_Hc) / shv;

                float cumw = 0.f, cumh = 0.f;
                float left = -TAILF, chl_run = -TAILF;
                float lw = -TAILF, wsel = 1.f, chl = -TAILF, hsel = 1.f;
                int idx = 0;
#pragma unroll
                for (int b = 0; b < NBINS; b++) {
                    float wb = MIN_Wc + uw[b] * isw;
                    float hb = MIN_Hc + uh[b] * ish;
                    cumw += wb; cumh += hb;
                    float cwr = (b == NBINS - 1) ? TAILF : 2.f * TAILF * cumw - TAILF;
                    float chr = (b == NBINS - 1) ? TAILF : 2.f * TAILF * cumh - TAILF;
                    bool inb = (xcv >= left) && ((xcv < cwr) || (b == NBINS - 1));
                    if (inb) { idx = b; lw = left; wsel = cwr - left; chl = chl_run; hsel = chr - chl_run; }
                    left = cwr; chl_run = chr;
                }
                float d0 = 1.f, d1 = 1.f;
                if (idx > 0) d0 = MIN_Dc + sp_softplus(rp[2 * NBINS + idx - 1]);
                if (idx < NBINS - 1) d1 = MIN_Dc + sp_softplus(rp[2 * NBINS + idx]);

                float delta = hsel / wsel;
                float th = (xcv - lw) / wsel;
                float omt = 1.f - th;
                float tomt = th * omt;
                float num = hsel * (delta * th * th + d0 * tomt);
                float den = delta + (d0 + d1 - 2.f * delta) * tomt;
                float y = chl + num / den;
                float dnum = delta * delta * (d1 * th * th + 2.f * delta * tomt + d0 * omt * omt);
                float lad = __logf(dnum) - 2.f * __logf(den);

                y = inside ? y : xr;
                lad = inside ? lad : 0.f;
                xs[srow * 17 + f] = y;
                lad_acc += lad;
            }
        }
    }

    // ---- write z (final frame) and logdet
    for (int t2 = ln; t2 < SPW * FDIM; t2 += 64) {
        int s = t2 / FDIM, i = t2 % FDIM;
        out[(size_t)(sbase + s) * FDIM + i] = xs[s * 17 + i];
    }
    float v = lad_acc;
    v += __shfl_xor(v, 1);
    if (fi == 0)
        out[(size_t)BATCH * FDIM + sbase + srow] = v;
}

extern "C" void kernel_launch(void* const* d_in, const int* in_sizes, int n_in,
                              void* d_out, int out_size, void* d_ws, size_t ws_size,
                              hipStream_t stream) {
    const float* x  = (const float*)d_in[0];
    const float* Wi = (const float*)d_in[1];
    const float* bI = (const float*)d_in[2];
    const float* Wr = (const float*)d_in[3];
    const float* bR = (const float*)d_in[4];
    const float* Wo = (const float*)d_in[5];
    const float* bO = (const float*)d_in[6];

    bf16_t* wfrag = (bf16_t*)d_ws;
    size_t woff = ((size_t)WFRAG_TOTAL * 2 + 255) & ~(size_t)255;
    float* bblob = (float*)((char*)d_ws + woff);

    const int totalP = WFRAG_TOTAL + BB_TOTAL;
    preproc_kernel<<<(totalP + 255) / 256, 256, 0, stream>>>(Wi, Wr, Wo, bI, bR, bO, wfrag, bblob);

    flow_kernel<<<BATCH / (4 * SPW), 256, 0, stream>>>(x, (float*)d_out, wfrag, bblob);
}

// Round 13
// 524.548 us; speedup vs baseline: 1.1366x; 1.1366x over previous
//
#include <hip/hip_runtime.h>
#include <hip/hip_bf16.h>

#define FDIM 15
#define HDIM 128
#define LNUM 12
#define NBINS 16
#define MDIM 47
#define FM 705
#define BATCH 65536
#define TAILF 3.0f
#define MIN_Wc 0.001f
#define MIN_Hc 0.001f
#define MIN_Dc 0.001f

typedef __bf16 bf16_t;
typedef __attribute__((ext_vector_type(8))) __bf16 bf16x8;
typedef __attribute__((ext_vector_type(4))) __bf16 bf16x4;
typedef __attribute__((ext_vector_type(4))) float f32x4;

// sparse fragment schedule (degree-sorted hidden units):
//   init 8 | residual 4*23=92 | out 111  => 211 frags, padded to 216 (27 chunks of 8)
#define FRAGS_USED 211
#define FRAGS_PAD 216
#define FRAG_ELEMS 512            // 64 lanes * 8 bf16 = 1 KB
#define CHUNK_FRAGS 8
#define CHUNK_ELEMS (CHUNK_FRAGS * FRAG_ELEMS)   // 8 KB
#define NCHUNKS 27
#define WFRAG_TOTAL (LNUM * FRAGS_PAD * FRAG_ELEMS)

// bias blob per layer: bI(128) | bR(512) | bOpad(15*48=720) = 1360 floats
#define BB_FLOATS 1360
#define BB_TOTAL (LNUM * BB_FLOATS)

#define SPW 32                    // samples per wave (2 N-tiles of 16)

// LDS pool layout (bytes)
#define WBUF_OFF   0
#define WBUF_BYTES (2 * CHUNK_ELEMS * 2)           // 16384
#define XSS_OFF    WBUF_BYTES
#define XSS_BYTES  (4 * SPW * 17 * 4)              // 8704
#define UNION_OFF  (XSS_OFF + XSS_BYTES)           // per-wave max(Bst 8704, raw 13312)
#define UNION_WV   13312
#define POOL_BYTES (UNION_OFF + 4 * UNION_WV)      // 78336

// degree-sorted permutation: pos -> original hidden index.
// deg(j) = j%14+1; r = deg-1; counts: r<2 -> 10, else 9.
__device__ __forceinline__ int perm_pos(int pos) {
    int r, o;
    if (pos < 20) { r = pos / 10; o = pos % 10; }
    else          { r = 2 + (pos - 20) / 9; o = (pos - 20) % 9; }
    return r + 14 * o;
}

__device__ __forceinline__ float sp_softplus(float u) {
    return (u > 20.f) ? u : __logf(1.f + __expf(u));
}

// ---------------- preproc: sparse-scheduled wfrag + permuted bias blob ----------------
__global__ void preproc_kernel(const float* __restrict__ Wi,
                               const float* __restrict__ Wr,
                               const float* __restrict__ Wo,
                               const float* __restrict__ bIg,
                               const float* __restrict__ bRg,
                               const float* __restrict__ bOg,
                               bf16_t* __restrict__ wfrag,
                               float* __restrict__ bblob) {
    const int RES_OFF[8] = {0, 1, 3, 5, 8, 11, 15, 19};
    const int RES_CNT[8] = {1, 2, 2, 3, 3, 4, 4, 4};
    const int OUT_OFF[15] = {0, 0, 3, 6, 9, 15, 21, 27, 36, 45, 54, 63, 75, 87, 99};
    const int OUT_CNT[15] = {0, 1, 1, 1, 2, 2, 2, 3, 3, 3, 3, 4, 4, 4, 4};

    int idx = blockIdx.x * blockDim.x + threadIdx.x;
    if (idx >= WFRAG_TOTAL) {
        int t = idx - WFRAG_TOTAL;
        if (t >= BB_TOTAL) return;
        int l = t / BB_FLOATS, r = t % BB_FLOATS;
        float v;
        if (r < 128) v = bIg[l * HDIM + perm_pos(r)];
        else if (r < 640) {
            int mat = (r - 128) >> 7, pos = (r - 128) & 127;
            v = bRg[(l * 4 + mat) * HDIM + perm_pos(pos)];
        } else {
            int q = r - 640, f = q / 48, j = q % 48;
            v = (j < 47) ? bOg[(size_t)l * FM + f * MDIM + j] : 0.f;
        }
        bblob[t] = v;
        return;
    }
    int j = idx & 7;
    int lane = (idx >> 3) & 63;
    int fg = idx >> 9;
    int g = fg % FRAGS_PAD;
    int l = fg / FRAGS_PAD;
    int quad = lane >> 4, n16 = lane & 15;
    int kk = quad * 8 + j;
    float val = 0.f;
    if (g < 8) {
        int n_orig = perm_pos(g * 16 + n16);
        if (kk < FDIM && (n_orig % 14) >= kk)
            val = Wi[(l * HDIM + n_orig) * FDIM + kk];
    } else if (g < 100) {
        int gg = g - 8;
        int mat = gg / 23, r = gg % 23;
        int mt = 7;
        while (mt > 0 && RES_OFF[mt] > r) mt--;
        int s = r - RES_OFF[mt];
        (void)RES_CNT;
        int j_orig = perm_pos(mt * 16 + n16);
        int k_orig = perm_pos(s * 32 + kk);
        if ((j_orig % 14) >= (k_orig % 14))
            val = Wr[((size_t)(l * 4 + mat) * HDIM + j_orig) * HDIM + k_orig];
    } else if (g < 211) {
        int gg = g - 100;
        int f = 14;
        while (f > 1 && OUT_OFF[f] > gg) f--;
        int q = gg - OUT_OFF[f];
        int cnt = OUT_CNT[f];
        int ty = q / cnt, s = q % cnt;
        int k_orig = perm_pos(s * 32 + kk);
        int o = (ty < 2) ? (f * MDIM + ty * 16 + n16)
                         : ((n16 < 15) ? (f * MDIM + 32 + n16) : -1);
        if (o >= 0 && f > (k_orig % 14))
            val = Wo[((size_t)l * FM + o) * HDIM + k_orig];
    }
    wfrag[idx] = (bf16_t)val;
}

// ---------------- per-layer kernel: sparse schedule, W=A act=B ----------------
__global__ __launch_bounds__(256, 2) void layer_kernel(
    const float* __restrict__ xin,
    float* __restrict__ xout,
    const float* __restrict__ ldin,
    float* __restrict__ ldout,
    const bf16_t* __restrict__ wl,
    const float* __restrict__ bias,
    int first) {

    constexpr int RES_CNT_C[8] = {1, 2, 2, 3, 3, 4, 4, 4};
    constexpr int OUT_CNT_C[15] = {0, 1, 1, 1, 2, 2, 2, 3, 3, 3, 3, 4, 4, 4, 4};

    __shared__ __align__(16) unsigned char pool[POOL_BYTES];

    const int tid = threadIdx.x;
    const int wv = tid >> 6, ln = tid & 63;
    const int quad = ln >> 4, n16 = ln & 15;
    const int fi = ln & 1, srow = ln >> 1;
    const int sbase = (blockIdx.x * 4 + wv) * SPW;

    bf16_t* wbuf = (bf16_t*)(pool + WBUF_OFF);
    float*  xs   = (float*)(pool + XSS_OFF) + wv * SPW * 17;      // [32][17]
    bf16_t* Bst  = (bf16_t*)(pool + UNION_OFF + wv * UNION_WV);   // [32][136]
    float*  raw  = (float*)(pool + UNION_OFF + wv * UNION_WV);    // [2][32][52]

    auto prefetch = [&](int c) {
        if (c >= NCHUNKS) return;
        const bf16_t* g = wl + (size_t)c * CHUNK_ELEMS + ln * 8;
        bf16_t* lb = wbuf + (c & 1) * CHUNK_ELEMS;
#pragma unroll
        for (int i = 0; i < 2; i++) {
            int off = (i * 4 + wv) * FRAG_ELEMS;   // wave-uniform LDS dest
            __builtin_amdgcn_global_load_lds(
                (const __attribute__((address_space(1))) uint32_t*)(g + off),
                (__attribute__((address_space(3))) uint32_t*)(lb + off), 16, 0, 0);
        }
    };

    prefetch(0);
    prefetch(1);

    // load x (32 samples x 15)
    for (int t = ln; t < SPW * FDIM; t += 64) {
        int s = t / FDIM, i = t % FDIM;
        xs[s * 17 + i] = xin[(size_t)(sbase + s) * FDIM + i];
    }

    __syncthreads();   // xs visible + chunks 0,1 drained

    // spline x-inputs (reversed frame): round p handles features 2p+fi
    float xc_pre[8];
#pragma unroll
    for (int p = 0; p < 8; p++) {
        int f = 2 * p + fi;
        xc_pre[p] = xs[srow * 17 + ((f < FDIM) ? (14 - f) : 0)];
    }
    // init-GEMM act B fragments from reversed xs, K padded 15->32
    bf16x8 a0[2];
#pragma unroll
    for (int T = 0; T < 2; T++)
#pragma unroll
        for (int j = 0; j < 8; j++) {
            int k = quad * 8 + j;
            a0[T][j] = (bf16_t)((k < FDIM) ? xs[(T * 16 + n16) * 17 + 14 - k] : 0.f);
        }

    int fp = 0;
    auto tick = [&]() {
        if (fp && (fp & 7) == 0) {
            __syncthreads();
            prefetch((fp >> 3) + 1);
        }
    };
    auto ldfrag = [&]() -> bf16x8 {
        return *(const bf16x8*)&wbuf[((fp >> 3) & 1) * CHUNK_ELEMS + (fp & 7) * FRAG_ELEMS + ln * 8];
    };

    f32x4 h[2][8];     // C-frag: rows = hidden (sorted space), col = sample n16

    // ---- init GEMM (frags 0..7)
    {
        f32x4 bbv[8];
#pragma unroll
        for (int mt = 0; mt < 8; mt++)
            bbv[mt] = *(const f32x4*)&bias[mt * 16 + quad * 4];
#pragma unroll
        for (int mt = 0; mt < 8; mt++) {
            tick();
            bf16x8 wf = ldfrag(); fp++;
            h[0][mt] = __builtin_amdgcn_mfma_f32_16x16x32_bf16(wf, a0[0], bbv[mt], 0, 0, 0);
            h[1][mt] = __builtin_amdgcn_mfma_f32_16x16x32_bf16(wf, a0[1], bbv[mt], 0, 0, 0);
        }
    }

    bf16x8 bf[2][4];   // staged act B-frags (k-tiles in sorted hidden space)
    auto stageB = [&](const f32x4 (*src)[8], bool relu) {
#pragma unroll
        for (int T = 0; T < 2; T++)
#pragma unroll
            for (int mt = 0; mt < 8; mt++) {
                bf16x4 pk;
#pragma unroll
                for (int r = 0; r < 4; r++) {
                    float v = src[T][mt][r];
                    if (relu) v = fmaxf(v, 0.f);
                    pk[r] = (bf16_t)v;
                }
                *(bf16x4*)&Bst[(T * 16 + n16) * 136 + mt * 16 + quad * 4] = pk;
            }
#pragma unroll
        for (int T = 0; T < 2; T++)
#pragma unroll
            for (int s = 0; s < 4; s++)
                bf[T][s] = *(const bf16x8*)&Bst[(T * 16 + n16) * 136 + s * 32 + quad * 8];
    };

    auto gemm128 = [&](f32x4 (*dst)[8], const float* bias_m, bool addto) {
        f32x4 bbv[8];
#pragma unroll
        for (int mt = 0; mt < 8; mt++)
            bbv[mt] = *(const f32x4*)&bias_m[mt * 16 + quad * 4];
#pragma unroll
        for (int mt = 0; mt < 8; mt++) {
            f32x4 acc0 = addto ? (dst[0][mt] + bbv[mt]) : bbv[mt];
            f32x4 acc1 = addto ? (dst[1][mt] + bbv[mt]) : bbv[mt];
#pragma unroll
            for (int s = 0; s < RES_CNT_C[mt]; s++) {
                tick();
                bf16x8 wf = ldfrag(); fp++;
                acc0 = __builtin_amdgcn_mfma_f32_16x16x32_bf16(wf, bf[0][s], acc0, 0, 0, 0);
                acc1 = __builtin_amdgcn_mfma_f32_16x16x32_bf16(wf, bf[1][s], acc1, 0, 0, 0);
            }
            dst[0][mt] = acc0;
            dst[1][mt] = acc1;
        }
    };

    // ---- residual blocks (frags 8..99)
    {
        f32x4 t[2][8];
        stageB(h, true);
        gemm128(t, bias + 128 + 0 * HDIM, false);
        stageB(t, true);
        gemm128(h, bias + 128 + 1 * HDIM, true);
        stageB(h, true);
        gemm128(t, bias + 128 + 2 * HDIM, false);
        stageB(t, true);
        gemm128(h, bias + 128 + 3 * HDIM, true);
    }

    // ---- out GEMM (frags 100..210) in 2-feature rounds + spline
    stageB(h, false);          // bf final; Bst region becomes raw
    const float* bO48 = bias + 640;
    float lad_acc = 0.f;

#pragma unroll
    for (int p = 0; p < 8; p++) {
        const int nf = (p < 7) ? 2 : 1;
#pragma unroll
        for (int ff = 0; ff < 2; ff++) {
            if (ff >= nf) break;
            const int f = 2 * p + ff;
            const int cnt = OUT_CNT_C[f];
            f32x4 bb3[3];
#pragma unroll
            for (int ty = 0; ty < 3; ty++)
                bb3[ty] = *(const f32x4*)&bO48[f * 48 + ty * 16 + quad * 4];
#pragma unroll
            for (int ty = 0; ty < 3; ty++) {
                f32x4 acc0 = bb3[ty];
                f32x4 acc1 = bb3[ty];
#pragma unroll
                for (int s = 0; s < cnt; s++) {
                    tick();
                    bf16x8 wf = ldfrag(); fp++;
                    acc0 = __builtin_amdgcn_mfma_f32_16x16x32_bf16(wf, bf[0][s], acc0, 0, 0, 0);
                    acc1 = __builtin_amdgcn_mfma_f32_16x16x32_bf16(wf, bf[1][s], acc1, 0, 0, 0);
                }
                // raw rows = ff*32 + sample (bank-uniform)
                *(f32x4*)&raw[(ff * 32 + n16) * 52 + ty * 16 + quad * 4] = acc0;
                *(f32x4*)&raw[(ff * 32 + 16 + n16) * 52 + ty * 16 + quad * 4] = acc1;
            }
        }

        // spline: lanes fi<nf handle (sample srow, feature 2p+fi)
        if (fi < nf) {
            int f = 2 * p + fi;
            const float* rp = &raw[(fi * 32 + srow) * 52];
            float xr = xc_pre[p];
            bool inside = (xr >= -TAILF) && (xr <= TAILF);
            float xcv = fminf(fmaxf(xr, -TAILF), TAILF);

            float uw[NBINS], uh[NBINS];
            {
                f32x4 v0 = *(const f32x4*)(rp + 0);
                f32x4 v1 = *(const f32x4*)(rp + 4);
                f32x4 v2 = *(const f32x4*)(rp + 8);
                f32x4 v3 = *(const f32x4*)(rp + 12);
                f32x4 w0 = *(const f32x4*)(rp + 16);
                f32x4 w1 = *(const f32x4*)(rp + 20);
                f32x4 w2 = *(const f32x4*)(rp + 24);
                f32x4 w3 = *(const f32x4*)(rp + 28);
#pragma unroll
                for (int i = 0; i < 4; i++) {
                    uw[i] = v0[i]; uw[4 + i] = v1[i]; uw[8 + i] = v2[i]; uw[12 + i] = v3[i];
                    uh[i] = w0[i]; uh[4 + i] = w1[i]; uh[8 + i] = w2[i]; uh[12 + i] = w3[i];
                }
            }
            float mw = -1e30f, mh = -1e30f;
#pragma unroll
            for (int i = 0; i < NBINS; i++) {
                mw = fmaxf(mw, uw[i]); mh = fmaxf(mh, uh[i]);
            }
            float swv = 0.f, shv = 0.f;
#pragma unroll
            for (int i = 0; i < NBINS; i++) {
                uw[i] = __expf(uw[i] - mw); swv += uw[i];
                uh[i] = __expf(uh[i] - mh); shv += uh[i];
            }
            float isw = (1.f - NBINS * MIN_Wc) / swv;
            float ish = (1.f - NBINS * MIN_Hc) / shv;

            float cumw = 0.f, cumh = 0.f;
            float left = -TAILF, chl_run = -TAILF;
            float lw = -TAILF, wsel = 1.f, chl = -TAILF, hsel = 1.f;
            int idx = 0;
#pragma unroll
            for (int b = 0; b < NBINS; b++) {
                float wb = MIN_Wc + uw[b] * isw;
                float hb = MIN_Hc + uh[b] * ish;
                cumw += wb; cumh += hb;
                float cwr = (b == NBINS - 1) ? TAILF : 2.f * TAILF * cumw - TAILF;
                float chr = (b == NBINS - 1) ? TAILF : 2.f * TAILF * cumh - TAILF;
                bool inb = (xcv >= left) && ((xcv < cwr) || (b == NBINS - 1));
                if (inb) { idx = b; lw = left; wsel = cwr - left; chl = chl_run; hsel = chr - chl_run; }
                left = cwr; chl_run = chr;
            }
            float d0 = 1.f, d1 = 1.f;
            if (idx > 0) d0 = MIN_Dc + sp_softplus(rp[2 * NBINS + idx - 1]);
            if (idx < NBINS - 1) d1 = MIN_Dc + sp_softplus(rp[2 * NBINS + idx]);

            float delta = hsel / wsel;
            float th = (xcv - lw) / wsel;
            float omt = 1.f - th;
            float tomt = th * omt;
            float num = hsel * (delta * th * th + d0 * tomt);
            float den = delta + (d0 + d1 - 2.f * delta) * tomt;
            float y = chl + num / den;
            float dnum = delta * delta * (d1 * th * th + 2.f * delta * tomt + d0 * omt * omt);
            float lad = __logf(dnum) - 2.f * __logf(den);

            y = inside ? y : xr;
            lad = inside ? lad : 0.f;
            xs[srow * 17 + f] = y;
            lad_acc += lad;
        }
    }

    // ---- write x carry
    for (int t2 = ln; t2 < SPW * FDIM; t2 += 64) {
        int s = t2 / FDIM, i = t2 % FDIM;
        xout[(size_t)(sbase + s) * FDIM + i] = xs[s * 17 + i];
    }
    // ---- logdet accumulate (fi pair sums)
    float v = lad_acc;
    v += __shfl_xor(v, 1);
    if (fi == 0) {
        size_t gs = (size_t)sbase + srow;
        float prev = first ? 0.f : ldin[gs];
        ldout[gs] = prev + v;
    }
}

extern "C" void kernel_launch(void* const* d_in, const int* in_sizes, int n_in,
                              void* d_out, int out_size, void* d_ws, size_t ws_size,
                              hipStream_t stream) {
    const float* x  = (const float*)d_in[0];
    const float* Wi = (const float*)d_in[1];
    const float* bI = (const float*)d_in[2];
    const float* Wr = (const float*)d_in[3];
    const float* bR = (const float*)d_in[4];
    const float* Wo = (const float*)d_in[5];
    const float* bO = (const float*)d_in[6];

    bf16_t* wfrag = (bf16_t*)d_ws;
    size_t woff = ((size_t)WFRAG_TOTAL * 2 + 255) & ~(size_t)255;
    float* bblob = (float*)((char*)d_ws + woff);
    float* xbuf  = bblob + BB_TOTAL;
    float* ldbuf = xbuf + (size_t)BATCH * FDIM;
    float* zout  = (float*)d_out;
    float* ldout_final = zout + (size_t)BATCH * FDIM;

    const int totalP = WFRAG_TOTAL + BB_TOTAL;
    preproc_kernel<<<(totalP + 255) / 256, 256, 0, stream>>>(Wi, Wr, Wo, bI, bR, bO, wfrag, bblob);

    for (int l = 0; l < LNUM; l++) {
        const float* xi = (l == 0) ? x : xbuf;
        float* xo = (l == LNUM - 1) ? zout : xbuf;
        float* ldo = (l == LNUM - 1) ? ldout_final : ldbuf;
        layer_kernel<<<BATCH / (4 * SPW), 256, 0, stream>>>(
            xi, xo, ldbuf, ldo,
            wfrag + (size_t)l * FRAGS_PAD * FRAG_ELEMS,
            bblob + (size_t)l * BB_FLOATS,
            (l == 0) ? 1 : 0);
    }
}

// Round 14
// 522.101 us; speedup vs baseline: 1.1420x; 1.0047x over previous
//
#include <hip/hip_runtime.h>
#include <hip/hip_bf16.h>

#define FDIM 15
#define HDIM 128
#define LNUM 12
#define NBINS 16
#define MDIM 47
#define FM 705
#define BATCH 65536
#define TAILF 3.0f
#define MIN_Wc 0.001f
#define MIN_Hc 0.001f
#define MIN_Dc 0.001f

typedef __bf16 bf16_t;
typedef __attribute__((ext_vector_type(8))) __bf16 bf16x8;
typedef __attribute__((ext_vector_type(4))) __bf16 bf16x4;
typedef __attribute__((ext_vector_type(4))) float f32x4;

// sparse fragment schedule (degree-sorted hidden units):
//   init 8 | residual 4*23=92 | out 111  => 211 frags, padded to 216 (27 chunks of 8)
#define FRAGS_USED 211
#define FRAGS_PAD 216
#define FRAG_ELEMS 512            // 64 lanes * 8 bf16 = 1 KB
#define CHUNK_FRAGS 8
#define CHUNK_ELEMS (CHUNK_FRAGS * FRAG_ELEMS)   // 8 KB
#define NCHUNKS 27
#define WFRAG_TOTAL (LNUM * FRAGS_PAD * FRAG_ELEMS)

// bias blob per layer: bI(128) | bR(512) | bOpad(15*48=720) = 1360 floats
#define BB_FLOATS 1360
#define BB_TOTAL (LNUM * BB_FLOATS)

#define SPW 32                    // samples per wave (2 N-tiles of 16)

// LDS pool layout (bytes)
#define WBUF_OFF   0
#define WBUF_BYTES (2 * CHUNK_ELEMS * 2)           // 16384
#define XSS_OFF    WBUF_BYTES
#define XSS_BYTES  (4 * SPW * 17 * 4)              // 8704
#define UNION_OFF  (XSS_OFF + XSS_BYTES)           // per-wave max(Bst 8704, raw 13312)
#define UNION_WV   13312
#define POOL_BYTES (UNION_OFF + 4 * UNION_WV)      // 78336

// degree-sorted permutation: pos -> original hidden index.
__device__ __forceinline__ int perm_pos(int pos) {
    int r, o;
    if (pos < 20) { r = pos / 10; o = pos % 10; }
    else          { r = 2 + (pos - 20) / 9; o = (pos - 20) % 9; }
    return r + 14 * o;
}

__device__ __forceinline__ float sp_softplus(float u) {
    return (u > 20.f) ? u : __logf(1.f + __expf(u));
}

// ---------------- preproc: sparse-scheduled wfrag + permuted bias blob ----------------
__global__ void preproc_kernel(const float* __restrict__ Wi,
                               const float* __restrict__ Wr,
                               const float* __restrict__ Wo,
                               const float* __restrict__ bIg,
                               const float* __restrict__ bRg,
                               const float* __restrict__ bOg,
                               bf16_t* __restrict__ wfrag,
                               float* __restrict__ bblob) {
    const int RES_OFF[8] = {0, 1, 3, 5, 8, 11, 15, 19};
    const int OUT_OFF[15] = {0, 0, 3, 6, 9, 15, 21, 27, 36, 45, 54, 63, 75, 87, 99};
    const int OUT_CNT[15] = {0, 1, 1, 1, 2, 2, 2, 3, 3, 3, 3, 4, 4, 4, 4};

    int idx = blockIdx.x * blockDim.x + threadIdx.x;
    if (idx >= WFRAG_TOTAL) {
        int t = idx - WFRAG_TOTAL;
        if (t >= BB_TOTAL) return;
        int l = t / BB_FLOATS, r = t % BB_FLOATS;
        float v;
        if (r < 128) v = bIg[l * HDIM + perm_pos(r)];
        else if (r < 640) {
            int mat = (r - 128) >> 7, pos = (r - 128) & 127;
            v = bRg[(l * 4 + mat) * HDIM + perm_pos(pos)];
        } else {
            int q = r - 640, f = q / 48, j = q % 48;
            v = (j < 47) ? bOg[(size_t)l * FM + f * MDIM + j] : 0.f;
        }
        bblob[t] = v;
        return;
    }
    int j = idx & 7;
    int lane = (idx >> 3) & 63;
    int fg = idx >> 9;
    int g = fg % FRAGS_PAD;
    int l = fg / FRAGS_PAD;
    int quad = lane >> 4, n16 = lane & 15;
    int kk = quad * 8 + j;
    float val = 0.f;
    if (g < 8) {
        int n_orig = perm_pos(g * 16 + n16);
        if (kk < FDIM && (n_orig % 14) >= kk)
            val = Wi[(l * HDIM + n_orig) * FDIM + kk];
    } else if (g < 100) {
        int gg = g - 8;
        int mat = gg / 23, r = gg % 23;
        int mt = 7;
        while (mt > 0 && RES_OFF[mt] > r) mt--;
        int s = r - RES_OFF[mt];
        int j_orig = perm_pos(mt * 16 + n16);
        int k_orig = perm_pos(s * 32 + kk);
        if ((j_orig % 14) >= (k_orig % 14))
            val = Wr[((size_t)(l * 4 + mat) * HDIM + j_orig) * HDIM + k_orig];
    } else if (g < 211) {
        int gg = g - 100;
        int f = 14;
        while (f > 1 && OUT_OFF[f] > gg) f--;
        int q = gg - OUT_OFF[f];
        int cnt = OUT_CNT[f];
        int ty = q / cnt, s = q % cnt;
        int k_orig = perm_pos(s * 32 + kk);
        int o = (ty < 2) ? (f * MDIM + ty * 16 + n16)
                         : ((n16 < 15) ? (f * MDIM + 32 + n16) : -1);
        if (o >= 0 && f > (k_orig % 14))
            val = Wo[((size_t)l * FM + o) * HDIM + k_orig];
    }
    wfrag[idx] = (bf16_t)val;
}

// ---------------- per-layer kernel: sparse schedule + chunk-bulk register staging ----------------
__global__ __launch_bounds__(256, 2) void layer_kernel(
    const float* __restrict__ xin,
    float* __restrict__ xout,
    const float* __restrict__ ldin,
    float* __restrict__ ldout,
    const bf16_t* __restrict__ wl,
    const float* __restrict__ bias,
    int first) {

    constexpr int RES_CNT_C[8] = {1, 2, 2, 3, 3, 4, 4, 4};
    constexpr int OUT_CNT_C[15] = {0, 1, 1, 1, 2, 2, 2, 3, 3, 3, 3, 4, 4, 4, 4};

    __shared__ __align__(16) unsigned char pool[POOL_BYTES];

    const int tid = threadIdx.x;
    const int wv = tid >> 6, ln = tid & 63;
    const int quad = ln >> 4, n16 = ln & 15;
    const int fi = ln & 1, srow = ln >> 1;
    const int sbase = (blockIdx.x * 4 + wv) * SPW;

    bf16_t* wbuf = (bf16_t*)(pool + WBUF_OFF);
    float*  xs   = (float*)(pool + XSS_OFF) + wv * SPW * 17;      // [32][17]
    bf16_t* Bst  = (bf16_t*)(pool + UNION_OFF + wv * UNION_WV);   // [32][136]
    float*  raw  = (float*)(pool + UNION_OFF + wv * UNION_WV);    // [2][32][52]

    auto prefetch = [&](int c) {
        if (c >= NCHUNKS) return;
        const bf16_t* g = wl + (size_t)c * CHUNK_ELEMS + ln * 8;
        bf16_t* lb = wbuf + (c & 1) * CHUNK_ELEMS;
#pragma unroll
        for (int i = 0; i < 2; i++) {
            int off = (i * 4 + wv) * FRAG_ELEMS;   // wave-uniform LDS dest
            __builtin_amdgcn_global_load_lds(
                (const __attribute__((address_space(1))) uint32_t*)(g + off),
                (__attribute__((address_space(3))) uint32_t*)(lb + off), 16, 0, 0);
        }
    };

    prefetch(0);
    prefetch(1);

    // load x (32 samples x 15)
    for (int t = ln; t < SPW * FDIM; t += 64) {
        int s = t / FDIM, i = t % FDIM;
        xs[s * 17 + i] = xin[(size_t)(sbase + s) * FDIM + i];
    }

    __syncthreads();   // xs visible + chunks 0,1 drained

    // spline x-inputs (reversed frame): round p handles features 2p+fi
    float xc_pre[8];
#pragma unroll
    for (int p = 0; p < 8; p++) {
        int f = 2 * p + fi;
        xc_pre[p] = xs[srow * 17 + ((f < FDIM) ? (14 - f) : 0)];
    }
    // init-GEMM act B fragments from reversed xs, K padded 15->32
    bf16x8 a0[2];
#pragma unroll
    for (int T = 0; T < 2; T++)
#pragma unroll
        for (int j = 0; j < 8; j++) {
            int k = quad * 8 + j;
            a0[T][j] = (bf16_t)((k < FDIM) ? xs[(T * 16 + n16) * 17 + 14 - k] : 0.f);
        }

    // ---- weight frag path: chunk-bulk register staging (8 ds_reads in flight per chunk)
    int fp = 0;
    bf16x8 Q[8];
    auto ldfrag = [&]() -> bf16x8 {
        if ((fp & 7) == 0) {
            if (fp) {
                __syncthreads();                 // chunk (fp/8) data valid; prev chunk free
                prefetch((fp >> 3) + 1);         // refill freed slot
            }
            const bf16_t* base = &wbuf[((fp >> 3) & 1) * CHUNK_ELEMS + ln * 8];
#pragma unroll
            for (int i = 0; i < 8; i++)
                Q[i] = *(const bf16x8*)(base + i * FRAG_ELEMS);
        }
        bf16x8 r = Q[fp & 7];
        fp++;
        return r;
    };

    f32x4 h[2][8];     // C-frag: rows = hidden (sorted space), col = sample n16

    // ---- init GEMM (frags 0..7)
    {
        f32x4 bbv[8];
#pragma unroll
        for (int mt = 0; mt < 8; mt++)
            bbv[mt] = *(const f32x4*)&bias[mt * 16 + quad * 4];
#pragma unroll
        for (int mt = 0; mt < 8; mt++) {
            bf16x8 wf = ldfrag();
            h[0][mt] = __builtin_amdgcn_mfma_f32_16x16x32_bf16(wf, a0[0], bbv[mt], 0, 0, 0);
            h[1][mt] = __builtin_amdgcn_mfma_f32_16x16x32_bf16(wf, a0[1], bbv[mt], 0, 0, 0);
        }
    }

    bf16x8 bf[2][4];   // staged act B-frags (k-tiles in sorted hidden space)
    auto stageB = [&](const f32x4 (*src)[8], bool relu) {
#pragma unroll
        for (int T = 0; T < 2; T++)
#pragma unroll
            for (int mt = 0; mt < 8; mt++) {
                bf16x4 pk;
#pragma unroll
                for (int r = 0; r < 4; r++) {
                    float v = src[T][mt][r];
                    if (relu) v = fmaxf(v, 0.f);
                    pk[r] = (bf16_t)v;
                }
                *(bf16x4*)&Bst[(T * 16 + n16) * 136 + mt * 16 + quad * 4] = pk;
            }
#pragma unroll
        for (int T = 0; T < 2; T++)
#pragma unroll
            for (int s = 0; s < 4; s++)
                bf[T][s] = *(const bf16x8*)&Bst[(T * 16 + n16) * 136 + s * 32 + quad * 8];
    };

    auto gemm128 = [&](f32x4 (*dst)[8], const float* bias_m, bool addto) {
        f32x4 bbv[8];
#pragma unroll
        for (int mt = 0; mt < 8; mt++)
            bbv[mt] = *(const f32x4*)&bias_m[mt * 16 + quad * 4];
#pragma unroll
        for (int mt = 0; mt < 8; mt++) {
            f32x4 acc0 = addto ? (dst[0][mt] + bbv[mt]) : bbv[mt];
            f32x4 acc1 = addto ? (dst[1][mt] + bbv[mt]) : bbv[mt];
#pragma unroll
            for (int s = 0; s < RES_CNT_C[mt]; s++) {
                bf16x8 wf = ldfrag();
                acc0 = __builtin_amdgcn_mfma_f32_16x16x32_bf16(wf, bf[0][s], acc0, 0, 0, 0);
                acc1 = __builtin_amdgcn_mfma_f32_16x16x32_bf16(wf, bf[1][s], acc1, 0, 0, 0);
            }
            dst[0][mt] = acc0;
            dst[1][mt] = acc1;
        }
    };

    // ---- residual blocks (frags 8..99)
    {
        f32x4 t[2][8];
        stageB(h, true);
        gemm128(t, bias + 128 + 0 * HDIM, false);
        stageB(t, true);
        gemm128(h, bias + 128 + 1 * HDIM, true);
        stageB(h, true);
        gemm128(t, bias + 128 + 2 * HDIM, false);
        stageB(t, true);
        gemm128(h, bias + 128 + 3 * HDIM, true);
    }

    // ---- out GEMM (frags 100..210) in 2-feature rounds + spline
    stageB(h, false);          // bf final; Bst region becomes raw
    const float* bO48 = bias + 640;
    float lad_acc = 0.f;

#pragma unroll
    for (int p = 0; p < 8; p++) {
        const int nf = (p < 7) ? 2 : 1;
#pragma unroll
        for (int ff = 0; ff < 2; ff++) {
            if (ff >= nf) break;
            const int f = 2 * p + ff;
            const int cnt = OUT_CNT_C[f];
            f32x4 bb3[3];
#pragma unroll
            for (int ty = 0; ty < 3; ty++)
                bb3[ty] = *(const f32x4*)&bO48[f * 48 + ty * 16 + quad * 4];
#pragma unroll
            for (int ty = 0; ty < 3; ty++) {
                f32x4 acc0 = bb3[ty];
                f32x4 acc1 = bb3[ty];
#pragma unroll
                for (int s = 0; s < cnt; s++) {
                    bf16x8 wf = ldfrag();
                    acc0 = __builtin_amdgcn_mfma_f32_16x16x32_bf16(wf, bf[0][s], acc0, 0, 0, 0);
                    acc1 = __builtin_amdgcn_mfma_f32_16x16x32_bf16(wf, bf[1][s], acc1, 0, 0, 0);
                }
                // raw rows = ff*32 + sample (bank-uniform)
                *(f32x4*)&raw[(ff * 32 + n16) * 52 + ty * 16 + quad * 4] = acc0;
                *(f32x4*)&raw[(ff * 32 + 16 + n16) * 52 + ty * 16 + quad * 4] = acc1;
            }
        }

        // spline: lanes fi<nf handle (sample srow, feature 2p+fi)
        if (fi < nf) {
            int f = 2 * p + fi;
            const float* rp = &raw[(fi * 32 + srow) * 52];
            float xr = xc_pre[p];
            bool inside = (xr >= -TAILF) && (xr <= TAILF);
            float xcv = fminf(fmaxf(xr, -TAILF), TAILF);

            float uw[NBINS], uh[NBINS];
            {
                f32x4 v0 = *(const f32x4*)(rp + 0);
                f32x4 v1 = *(const f32x4*)(rp + 4);
                f32x4 v2 = *(const f32x4*)(rp + 8);
                f32x4 v3 = *(const f32x4*)(rp + 12);
                f32x4 w0 = *(const f32x4*)(rp + 16);
                f32x4 w1 = *(const f32x4*)(rp + 20);
                f32x4 w2 = *(const f32x4*)(rp + 24);
                f32x4 w3 = *(const f32x4*)(rp + 28);
#pragma unroll
                for (int i = 0; i < 4; i++) {
                    uw[i] = v0[i]; uw[4 + i] = v1[i]; uw[8 + i] = v2[i]; uw[12 + i] = v3[i];
                    uh[i] = w0[i]; uh[4 + i] = w1[i]; uh[8 + i] = w2[i]; uh[12 + i] = w3[i];
                }
            }
            float mw = -1e30f, mh = -1e30f;
#pragma unroll
            for (int i = 0; i < NBINS; i++) {
                mw = fmaxf(mw, uw[i]); mh = fmaxf(mh, uh[i]);
            }
            float swv = 0.f, shv = 0.f;
#pragma unroll
            for (int i = 0; i < NBINS; i++) {
                uw[i] = __expf(uw[i] - mw); swv += uw[i];
                uh[i] = __expf(uh[i] - mh); shv += uh[i];
            }
            float isw = (1.f - NBINS * MIN_Wc) / swv;
            float ish = (1.f - NBINS * MIN_Hc) / shv;

            float cumw = 0.f, cumh = 0.f;
            float left = -TAILF, chl_run = -TAILF;
            float lw = -TAILF, wsel = 1.f, chl = -TAILF, hsel = 1.f;
            int idx = 0;
#pragma unroll
            for (int b = 0; b < NBINS; b++) {
                float wb = MIN_Wc + uw[b] * isw;
                float hb = MIN_Hc + uh[b] * ish;
                cumw += wb; cumh += hb;
                float cwr = (b == NBINS - 1) ? TAILF : 2.f * TAILF * cumw - TAILF;
                float chr = (b == NBINS - 1) ? TAILF : 2.f * TAILF * cumh - TAILF;
                bool inb = (xcv >= left) && ((xcv < cwr) || (b == NBINS - 1));
                if (inb) { idx = b; lw = left; wsel = cwr - left; chl = chl_run; hsel = chr - chl_run; }
                left = cwr; chl_run = chr;
            }
            float d0 = 1.f, d1 = 1.f;
            if (idx > 0) d0 = MIN_Dc + sp_softplus(rp[2 * NBINS + idx - 1]);
            if (idx < NBINS - 1) d1 = MIN_Dc + sp_softplus(rp[2 * NBINS + idx]);

            float delta = hsel / wsel;
            float th = (xcv - lw) / wsel;
            float omt = 1.f - th;
            float tomt = th * omt;
            float num = hsel * (delta * th * th + d0 * tomt);
            float den = delta + (d0 + d1 - 2.f * delta) * tomt;
            float y = chl + num / den;
            float dnum = delta * delta * (d1 * th * th + 2.f * delta * tomt + d0 * omt * omt);
            float lad = __logf(dnum) - 2.f * __logf(den);

            y = inside ? y : xr;
            lad = inside ? lad : 0.f;
            xs[srow * 17 + f] = y;
            lad_acc += lad;
        }
    }

    // ---- write x carry
    for (int t2 = ln; t2 < SPW * FDIM; t2 += 64) {
        int s = t2 / FDIM, i = t2 % FDIM;
        xout[(size_t)(sbase + s) * FDIM + i] = xs[s * 17 + i];
    }
    // ---- logdet accumulate (fi pair sums)
    float v = lad_acc;
    v += __shfl_xor(v, 1);
    if (fi == 0) {
        size_t gs = (size_t)sbase + srow;
        float prev = first ? 0.f : ldin[gs];
        ldout[gs] = prev + v;
    }
}

extern "C" void kernel_launch(void* const* d_in, const int* in_sizes, int n_in,
                              void* d_out, int out_size, void* d_ws, size_t ws_size,
                              hipStream_t stream) {
    const float* x  = (const float*)d_in[0];
    const float* Wi = (const float*)d_in[1];
    const float* bI = (const float*)d_in[2];
    const float* Wr = (const float*)d_in[3];
    const float* bR = (const float*)d_in[4];
    const float* Wo = (const float*)d_in[5];
    const float* bO = (const float*)d_in[6];

    bf16_t* wfrag = (bf16_t*)d_ws;
    size_t woff = ((size_t)WFRAG_TOTAL * 2 + 255) & ~(size_t)255;
    float* bblob = (float*)((char*)d_ws + woff);
    float* xbuf  = bblob + BB_TOTAL;
    float* ldbuf = xbuf + (size_t)BATCH * FDIM;
    float* zout  = (float*)d_out;
    float* ldout_final = zout + (size_t)BATCH * FDIM;

    const int totalP = WFRAG_TOTAL + BB_TOTAL;
    preproc_kernel<<<(totalP + 255) / 256, 256, 0, stream>>>(Wi, Wr, Wo, bI, bR, bO, wfrag, bblob);

    for (int l = 0; l < LNUM; l++) {
        const float* xi = (l == 0) ? x : xbuf;
        float* xo = (l == LNUM - 1) ? zout : xbuf;
        float* ldo = (l == LNUM - 1) ? ldout_final : ldbuf;
        layer_kernel<<<BATCH / (4 * SPW), 256, 0, stream>>>(
            xi, xo, ldbuf, ldo,
            wfrag + (size_t)l * FRAGS_PAD * FRAG_ELEMS,
            bblob + (size_t)l * BB_FLOATS,
            (l == 0) ? 1 : 0);
    }
}